// Round 2
// baseline (848.830 us; speedup 1.0000x reference)
//
#include <hip/hip_runtime.h>
#include <hip/hip_bf16.h>

// Potts energy kernel for MI355X.
// B=2, N=4096, K=48, Q=20.
// Outputs (flat concat): U (B,) then U_i (B,N,Q), fp32.
//
// J (629 MB) dominates; the column gather touches ~all cache lines of each
// 20x20 block anyway, so stream J at full BW. R2 structure: each thread owns
// whole 20-float rows of fixed q (t<240: q=t%20, k=t/20+12i), 20 independent
// float4 loads in flight per thread, branchless register select of row[sj[k]],
// private accumulation, ONE LDS atomic per thread at the end.

constexpr int Bc = 2;
constexpr int Nc = 4096;
constexpr int Kc = 48;
constexpr int Qc = 20;
constexpr int NODE_FLOATS = Kc * Qc * Qc;      // 19200

__global__ __launch_bounds__(256) void potts_node_kernel(
    const int*   __restrict__ S,
    const float* __restrict__ h,
    const float* __restrict__ J,
    const int*   __restrict__ edge_idx,
    float*       __restrict__ U_i_out,   // (B*N*Q)
    float*       __restrict__ node_c)    // (B*N) per-node scalar contribution
{
    const int node = blockIdx.x;          // 0 .. B*N-1
    const int b    = node >> 12;          // node / N (N=4096)
    const int tid  = threadIdx.x;

    __shared__ float Jl[Qc];
    __shared__ int   sj[Kc];
    __shared__ int   s_i_sh;

    if (tid < Qc) Jl[tid] = 0.0f;
    if (tid < Kc) {
        int e = edge_idx[node * Kc + tid];
        sj[tid] = S[b * Nc + e];
    }
    if (tid == 0) s_i_sh = S[node];
    __syncthreads();

    if (tid < 240) {
        const int k0 = tid / 20;          // 0..11
        const int q  = tid - k0 * 20;     // 0..19
        const float* base = J + (size_t)node * NODE_FLOATS;
        float acc = 0.0f;
        #pragma unroll
        for (int i = 0; i < 4; ++i) {
            const int k = k0 + 12 * i;            // covers 0..47
            const int s = sj[k];
            const float4* rp = (const float4*)(base + (k * 20 + q) * 20);
            float4 r0 = rp[0], r1 = rp[1], r2 = rp[2], r3 = rp[3], r4 = rp[4];
            // branchless select of element s from the 20-float row
            float4 g = (s < 8) ? ((s < 4) ? r0 : r1)
                               : ((s < 12) ? r2 : ((s < 16) ? r3 : r4));
            const int c = s & 3;
            float val = (c == 0) ? g.x : (c == 1) ? g.y : (c == 2) ? g.z : g.w;
            acc += val;
        }
        atomicAdd(&Jl[q], acc);           // one atomic per thread, 12-way/address
    }
    __syncthreads();

    if (tid < Qc) {
        float ji = Jl[tid];
        float ui = h[node * Qc + tid] + ji;
        U_i_out[node * Qc + tid] = ui;
        if (tid == s_i_sh) {
            // U contribution: (h[s]+J_i[s]) - 0.5*J_i[s] = ui - 0.5*ji
            node_c[node] = ui - 0.5f * ji;
        }
    }
}

__global__ __launch_bounds__(256) void potts_reduce_kernel(
    const float* __restrict__ node_c, float* __restrict__ U)
{
    const int b   = blockIdx.x;
    const int tid = threadIdx.x;
    float s = 0.0f;
    for (int i = tid; i < Nc; i += 256) s += node_c[b * Nc + i];
    #pragma unroll
    for (int off = 32; off > 0; off >>= 1) s += __shfl_down(s, off, 64);
    __shared__ float ws[4];
    if ((tid & 63) == 0) ws[tid >> 6] = s;
    __syncthreads();
    if (tid == 0) U[b] = ws[0] + ws[1] + ws[2] + ws[3];
}

extern "C" void kernel_launch(void* const* d_in, const int* in_sizes, int n_in,
                              void* d_out, int out_size, void* d_ws, size_t ws_size,
                              hipStream_t stream) {
    const int*   S        = (const int*)  d_in[0];
    const float* h        = (const float*)d_in[1];
    const float* J        = (const float*)d_in[2];
    const int*   edge_idx = (const int*)  d_in[3];

    float* out    = (float*)d_out;
    float* U      = out;        // 2 floats
    float* U_i    = out + Bc;   // B*N*Q floats
    float* node_c = (float*)d_ws;

    potts_node_kernel<<<Bc * Nc, 256, 0, stream>>>(S, h, J, edge_idx, U_i, node_c);
    potts_reduce_kernel<<<Bc, 256, 0, stream>>>(node_c, U);
}

// Round 3
// 796.379 us; speedup vs baseline: 1.0659x; 1.0659x over previous
//
#include <hip/hip_runtime.h>
#include <hip/hip_bf16.h>

// Potts energy kernel for MI355X.
// B=2, N=4096, K=48, Q=20.
// Outputs (flat concat): U (B,) then U_i (B,N,Q), fp32.
//
// J (629 MB) dominates and every cache line of each 20x20 block is touched by
// the column gather, so the roofline is one coalesced pass over J (~105 us).
// R3: R1's fully-coalesced float4 stream (best measured) with a clean loop:
// 320 threads/block -> 4800/320 = 15 iterations exactly (no ragged tail),
// unroll 5 for 5 independent 1KB wave-loads in flight. Conditional one-lane
// LDS atomic does the column select (~1/5 lanes active).

constexpr int Bc = 2;
constexpr int Nc = 4096;
constexpr int Kc = 48;
constexpr int Qc = 20;
constexpr int NODE_FLOATS = Kc * Qc * Qc;      // 19200
constexpr int NODE_F4     = NODE_FLOATS / 4;   // 4800
constexpr int TPB         = 320;               // 5 waves; 4800 % 320 == 0

__global__ __launch_bounds__(TPB) void potts_node_kernel(
    const int*   __restrict__ S,
    const float* __restrict__ h,
    const float* __restrict__ J,
    const int*   __restrict__ edge_idx,
    float*       __restrict__ U_i_out,   // (B*N*Q)
    float*       __restrict__ node_c)    // (B*N) per-node scalar contribution
{
    const int node = blockIdx.x;          // 0 .. B*N-1
    const int b    = node >> 12;          // node / N (N=4096)
    const int tid  = threadIdx.x;

    __shared__ float Jl[Qc];
    __shared__ int   sj[Kc];
    __shared__ int   s_i_sh;

    if (tid < Qc) Jl[tid] = 0.0f;
    if (tid < Kc) {
        int e = edge_idx[node * Kc + tid];
        sj[tid] = S[b * Nc + e];
    }
    if (tid == 0) s_i_sh = S[node];
    __syncthreads();

    // Stream this node's 75 KB J slice fully coalesced, 15 exact iterations.
    const float4* Jb = (const float4*)(J + (size_t)node * NODE_FLOATS);
    #pragma unroll 5
    for (int j = 0; j < NODE_F4 / TPB; ++j) {
        const int m = tid + j * TPB;
        float4 v = Jb[m];
        // flat float index f = 4*m ; f = k*400 + q*20 + s ; s0 in {0,4,8,12,16}
        int k  = m / 100;              // 100 float4 per k
        int r  = m - k * 100;
        int q  = r / 5;                // 5 float4 per q
        int s0 = (r - q * 5) << 2;
        int d  = sj[k] - s0;
        if ((unsigned)d < 4u) {
            float val = (d == 0) ? v.x : (d == 1) ? v.y : (d == 2) ? v.z : v.w;
            atomicAdd(&Jl[q], val);
        }
    }
    __syncthreads();

    if (tid < Qc) {
        float ji = Jl[tid];
        float ui = h[node * Qc + tid] + ji;
        U_i_out[node * Qc + tid] = ui;
        if (tid == s_i_sh) {
            // U contribution: (h[s]+J_i[s]) - 0.5*J_i[s] = ui - 0.5*ji
            node_c[node] = ui - 0.5f * ji;
        }
    }
}

__global__ __launch_bounds__(256) void potts_reduce_kernel(
    const float* __restrict__ node_c, float* __restrict__ U)
{
    const int b   = blockIdx.x;
    const int tid = threadIdx.x;
    float s = 0.0f;
    for (int i = tid; i < Nc; i += 256) s += node_c[b * Nc + i];
    #pragma unroll
    for (int off = 32; off > 0; off >>= 1) s += __shfl_down(s, off, 64);
    __shared__ float ws[4];
    if ((tid & 63) == 0) ws[tid >> 6] = s;
    __syncthreads();
    if (tid == 0) U[b] = ws[0] + ws[1] + ws[2] + ws[3];
}

extern "C" void kernel_launch(void* const* d_in, const int* in_sizes, int n_in,
                              void* d_out, int out_size, void* d_ws, size_t ws_size,
                              hipStream_t stream) {
    const int*   S        = (const int*)  d_in[0];
    const float* h        = (const float*)d_in[1];
    const float* J        = (const float*)d_in[2];
    const int*   edge_idx = (const int*)  d_in[3];

    float* out    = (float*)d_out;
    float* U      = out;        // 2 floats
    float* U_i    = out + Bc;   // B*N*Q floats
    float* node_c = (float*)d_ws;

    potts_node_kernel<<<Bc * Nc, TPB, 0, stream>>>(S, h, J, edge_idx, U_i, node_c);
    potts_reduce_kernel<<<Bc, 256, 0, stream>>>(node_c, U);
}